// Round 2
// baseline (2425.565 us; speedup 1.0000x reference)
//
#include <hip/hip_runtime.h>

typedef unsigned short ushort_t;
typedef unsigned int uint_t;
typedef __attribute__((ext_vector_type(8))) short short8;
typedef __attribute__((ext_vector_type(4))) float f32x4;

static constexpr int V = 32000, H = 512, HALFD = 256, LSEQ = 1024, BB = 64;
static constexpr int RCH = 8192;                 // rows per encoder chunk

__device__ __forceinline__ ushort_t f2bf(float f) {
    uint_t u = __float_as_uint(f);
    u = (u + 0x7FFFu + ((u >> 16) & 1u)) >> 16;
    return (ushort_t)u;
}
__device__ __forceinline__ float bf2f(ushort_t u) {
    return __uint_as_float(((uint_t)u) << 16);
}

// ---------------- weight transpose + fp32->bf16 convert: Wt[n][k] = bf16(W[k][n]) --
__global__ void transpose_cvt(const float* __restrict__ W, ushort_t* __restrict__ Wt,
                              int K, int N) {
    __shared__ float tile[32][33];
    int k0 = blockIdx.y * 32, n0 = blockIdx.x * 32;
    int tx = threadIdx.x & 31, ty = threadIdx.x >> 5;   // 256 threads: ty 0..7
    #pragma unroll
    for (int i = 0; i < 32; i += 8)
        tile[ty + i][tx] = W[(size_t)(k0 + ty + i) * N + n0 + tx];
    __syncthreads();
    #pragma unroll
    for (int i = 0; i < 32; i += 8)
        Wt[(size_t)(n0 + ty + i) * K + k0 + tx] = f2bf(tile[tx][ty + i]);
}

// ---------------- embedding gather (chunk): e bf16 --------------------------------
__global__ void gather_kernel(const int* __restrict__ seq, const float* __restrict__ embed,
                              ushort_t* __restrict__ ebf) {
    int row = blockIdx.x;
    int tok = seq[row];
    float4 v = ((const float4*)(embed + (size_t)tok * H))[threadIdx.x];
    ushort4 o;
    o.x = f2bf(v.x); o.y = f2bf(v.y); o.z = f2bf(v.z); o.w = f2bf(v.w);
    ((ushort4*)(ebf + (size_t)row * H))[threadIdx.x] = o;
}

// ---------------- bf16 MFMA GEMM:  C = f(A[MxK] @ Bt[NxK]^T + bias (+res)) --------
// MODE: 0 = plain, 1 = relu, 3 = +residual(bf16). Output bf16.
template <int MODE>
__global__ __launch_bounds__(256) void mfma_gemm(
        const ushort_t* __restrict__ A, const ushort_t* __restrict__ Bt,
        const float* __restrict__ bias, const ushort_t* __restrict__ res,
        ushort_t* __restrict__ Cout, int N, int K) {
    __shared__ __align__(16) ushort_t Al[128][40];   // pad 32->40 kills 8-way conflicts
    __shared__ __align__(16) ushort_t Bl[128][40];
    int t = threadIdx.x;
    int m0 = blockIdx.y * 128, n0 = blockIdx.x * 128;
    int lane = t & 63, wid = t >> 6;
    int wm = (wid & 1) * 64, wn = (wid >> 1) * 64;
    int lid = lane & 15, quad = lane >> 4;
    int srow = t >> 2, skq = (t & 3) * 8;            // staging: 4 threads/row, 8 bf16 each

    f32x4 acc[4][4];
    #pragma unroll
    for (int i = 0; i < 4; ++i)
        #pragma unroll
        for (int j = 0; j < 4; ++j)
            acc[i][j] = (f32x4){0.f, 0.f, 0.f, 0.f};

    for (int k0 = 0; k0 < K; k0 += 32) {
        short8 a0 = *(const short8*)(A + (size_t)(m0 + srow) * K + k0 + skq);
        short8 a1 = *(const short8*)(A + (size_t)(m0 + 64 + srow) * K + k0 + skq);
        short8 b0 = *(const short8*)(Bt + (size_t)(n0 + srow) * K + k0 + skq);
        short8 b1 = *(const short8*)(Bt + (size_t)(n0 + 64 + srow) * K + k0 + skq);
        __syncthreads();
        *(short8*)&Al[srow][skq]      = a0;
        *(short8*)&Al[64 + srow][skq] = a1;
        *(short8*)&Bl[srow][skq]      = b0;
        *(short8*)&Bl[64 + srow][skq] = b1;
        __syncthreads();
        short8 af[4], bfr[4];
        #pragma unroll
        for (int i = 0; i < 4; ++i)
            af[i] = *(const short8*)&Al[wm + i * 16 + lid][quad * 8];
        #pragma unroll
        for (int i = 0; i < 4; ++i)
            bfr[i] = *(const short8*)&Bl[wn + i * 16 + lid][quad * 8];
        #pragma unroll
        for (int mt = 0; mt < 4; ++mt)
            #pragma unroll
            for (int nt = 0; nt < 4; ++nt)
                acc[mt][nt] = __builtin_amdgcn_mfma_f32_16x16x32_bf16(
                    af[mt], bfr[nt], acc[mt][nt], 0, 0, 0);
    }
    // epilogue: C/D layout col=lane&15, row=quad*4+reg  [m89/m91-verified]
    #pragma unroll
    for (int mt = 0; mt < 4; ++mt) {
        #pragma unroll
        for (int nt = 0; nt < 4; ++nt) {
            #pragma unroll
            for (int rg = 0; rg < 4; ++rg) {
                int row = m0 + wm + mt * 16 + quad * 4 + rg;
                int col = n0 + wn + nt * 16 + lid;
                float v = acc[mt][nt][rg] + bias[col];
                if (MODE == 1) v = fmaxf(v, 0.f);
                if (MODE == 3) v += bf2f(res[(size_t)row * N + col]);
                Cout[(size_t)row * N + col] = f2bf(v);
            }
        }
    }
}

// ---------------- LayerNorm over H=512 (bf16 in-place), one wave per row ----------
__global__ void ln_kernel(ushort_t* X, const float* __restrict__ g,
                          const float* __restrict__ bta) {
    int row = blockIdx.x * 4 + (threadIdx.x >> 6);
    int lane = threadIdx.x & 63;
    ushort_t* xr = X + (size_t)row * H + lane * 8;
    short8 xv = *(short8*)xr;
    float x[8];
    #pragma unroll
    for (int j = 0; j < 8; ++j) x[j] = bf2f((ushort_t)xv[j]);
    float s = 0.f, ss = 0.f;
    #pragma unroll
    for (int j = 0; j < 8; ++j) { s += x[j]; ss += x[j] * x[j]; }
    #pragma unroll
    for (int d = 1; d < 64; d <<= 1) { s += __shfl_xor(s, d); ss += __shfl_xor(ss, d); }
    float mu = s * (1.f / 512.f);
    float var = ss * (1.f / 512.f) - mu * mu;
    float rstd = rsqrtf(var + 1e-5f);
    float4 g0 = *(const float4*)(g + lane * 8);
    float4 g1 = *(const float4*)(g + lane * 8 + 4);
    float4 b0 = *(const float4*)(bta + lane * 8);
    float4 b1 = *(const float4*)(bta + lane * 8 + 4);
    float gg[8] = {g0.x, g0.y, g0.z, g0.w, g1.x, g1.y, g1.z, g1.w};
    float bb[8] = {b0.x, b0.y, b0.z, b0.w, b1.x, b1.y, b1.z, b1.w};
    short8 o;
    #pragma unroll
    for (int j = 0; j < 8; ++j)
        o[j] = (short)f2bf((x[j] - mu) * rstd * gg[j] + bb[j]);
    *(short8*)xr = o;
}

// ---------------- beta[row] = sum(k^2) + 1e-6 (bf16 input), one wave per row ------
__global__ void beta_kernel(const ushort_t* __restrict__ k, float* __restrict__ beta) {
    int row = blockIdx.x * 4 + (threadIdx.x >> 6);
    int lane = threadIdx.x & 63;
    ushort4 a = *(const ushort4*)(k + (size_t)row * HALFD + lane * 4);
    float ax = bf2f(a.x), ay = bf2f(a.y), az = bf2f(a.z), aw = bf2f(a.w);
    float s = ax * ax + ay * ay + az * az + aw * aw;
    #pragma unroll
    for (int d = 1; d < 64; d <<= 1) s += __shfl_xor(s, d);
    if (lane == 0) beta[row] = s + 1e-6f;
}

// ---------------- sequential delta-rule scan --------------------------------------
// grid 256: blk = b*4 + mat*2 + half. WG owns 128 rows x 256 cols of M in registers.
// thread t: local row t>>3, col chunk (t&7)*32 .. +32
__global__ __launch_bounds__(1024) void scan_kernel(
        const ushort_t* __restrict__ ks, const ushort_t* __restrict__ ke,
        const float* __restrict__ beta_s, const float* __restrict__ beta_e,
        float* __restrict__ c) {
    int blk = blockIdx.x;
    int b = blk >> 2, mat = (blk >> 1) & 1, half = blk & 1;
    const ushort_t* Kp = (mat ? ke : ks) + (size_t)b * LSEQ * HALFD;
    const float* Bp = (mat ? beta_e : beta_s) + (size_t)b * LSEQ;
    int t = threadIdx.x, lr = t >> 3, q = t & 7;
    int r = half * 128 + lr;
    __shared__ __align__(16) float kb[2][264];       // 256 k values + beta at [256]
    float M[32];
    #pragma unroll
    for (int i = 0; i < 32; ++i) M[i] = 0.f;
    if (t < 32) {
        short8 kv = *(const short8*)(Kp + t * 8);
        #pragma unroll
        for (int j = 0; j < 8; ++j) kb[0][t * 8 + j] = bf2f((ushort_t)kv[j]);
    }
    if (t == 32) kb[0][256] = Bp[0];
    int cur = 0;
    const float invL = 1.0f / 1024.0f;
    for (int s = 0; s < LSEQ - 1; ++s) {
        __syncthreads();
        int nxt = cur ^ 1;
        if (t < 32) {
            short8 kv = *(const short8*)(Kp + (size_t)(s + 1) * HALFD + t * 8);
            #pragma unroll
            for (int j = 0; j < 8; ++j) kb[nxt][t * 8 + j] = bf2f((ushort_t)kv[j]);
        }
        if (t == 32) kb[nxt][256] = Bp[s + 1];
        float kq[32];
        #pragma unroll
        for (int i = 0; i < 8; ++i) {
            float4 kv = *(float4*)&kb[cur][q * 32 + i * 4];
            kq[i * 4 + 0] = kv.x; kq[i * 4 + 1] = kv.y;
            kq[i * 4 + 2] = kv.z; kq[i * 4 + 3] = kv.w;
        }
        float pd = 0.f;
        #pragma unroll
        for (int i = 0; i < 32; ++i) pd += M[i] * kq[i];
        pd += __shfl_xor(pd, 1); pd += __shfl_xor(pd, 2); pd += __shfl_xor(pd, 4);
        float beta = kb[cur][256];
        float kr = kb[cur][r];
        float dv = kr - pd / beta;
        float a = mat ? dv * (float)(s + 1) * invL : dv;
        #pragma unroll
        for (int i = 0; i < 32; ++i) M[i] += a * kq[i];
        cur = nxt;
    }
    __syncthreads();                                  // final matvec with k[L-1]
    float pd = 0.f;
    #pragma unroll
    for (int i = 0; i < 32; ++i) pd += M[i] * kb[cur][q * 32 + i];
    pd += __shfl_xor(pd, 1); pd += __shfl_xor(pd, 2); pd += __shfl_xor(pd, 4);
    if (q == 0) c[(size_t)b * 512 + mat * 256 + r] = pd;
}

// ---------------- output GEMM: out[64x32000] = c[64x512] @ W[512x32000] + b -------
__global__ __launch_bounds__(256) void out_gemm(
        const float* __restrict__ c, const float* __restrict__ W,
        const float* __restrict__ bias, float* __restrict__ out) {
    __shared__ __align__(16) float cl[32][64];
    int v = blockIdx.x * 256 + threadIdx.x;           // 125*256 = 32000 exactly
    int b0 = blockIdx.y * 32;
    float acc[32];
    #pragma unroll
    for (int b = 0; b < 32; ++b) acc[b] = 0.f;
    for (int kc = 0; kc < 512; kc += 64) {
        __syncthreads();
        for (int i = threadIdx.x; i < 32 * 16; i += 256) {
            int b = i >> 4, qq = (i & 15) * 4;
            *(float4*)&cl[b][qq] = *(const float4*)(c + (size_t)(b0 + b) * 512 + kc + qq);
        }
        __syncthreads();
        for (int kk = 0; kk < 64; ++kk) {
            float wv = W[(size_t)(kc + kk) * V + v];
            #pragma unroll
            for (int b = 0; b < 32; ++b) acc[b] += cl[b][kk] * wv;
        }
    }
    #pragma unroll
    for (int b = 0; b < 32; ++b) out[(size_t)(b0 + b) * V + v] = acc[b] + bias[v];
}

// ---------------- launch ----------------------------------------------------------
extern "C" void kernel_launch(void* const* d_in, const int* in_sizes, int n_in,
                              void* d_out, int out_size, void* d_ws, size_t ws_size,
                              hipStream_t stream) {
    const int*   seq    = (const int*)d_in[0];
    const float* embed  = (const float*)d_in[1];
    const float* ff_w1  = (const float*)d_in[2];
    const float* ff_b1  = (const float*)d_in[3];
    const float* ff_w2  = (const float*)d_in[4];
    const float* ff_b2  = (const float*)d_in[5];
    const float* ln_g   = (const float*)d_in[6];
    const float* ln_b   = (const float*)d_in[7];
    const float* sem_w  = (const float*)d_in[8];
    const float* sem_b  = (const float*)d_in[9];
    const float* epi_w  = (const float*)d_in[10];
    const float* epi_b  = (const float*)d_in[11];
    const float* out_w  = (const float*)d_in[12];
    const float* out_b  = (const float*)d_in[13];
    float* outp = (float*)d_out;

    const int ML = BB * LSEQ;                         // 65536 rows
    // workspace layout (~91.1 MB total)
    char* w = (char*)d_ws;
    ushort_t* ks_bf = (ushort_t*)(w + 0);             // 33554432 B (65536x256 bf16)
    ushort_t* ke_bf = (ushort_t*)(w + 33554432);      // 33554432 B
    ushort_t* ebc   = (ushort_t*)(w + 67108864);      //  8388608 B (8192x512 bf16, e/x/h)
    ushort_t* t1c   = (ushort_t*)(w + 75497472);      // 16777216 B (8192x1024 bf16)
    ushort_t* w1t   = (ushort_t*)(w + 92274688);      //  1048576 B
    ushort_t* w2t   = (ushort_t*)(w + 93323264);      //  1048576 B
    ushort_t* semt  = (ushort_t*)(w + 94371840);      //   262144 B
    ushort_t* epit  = (ushort_t*)(w + 94633984);      //   262144 B
    float*    bet_s = (float*)(w + 94896128);         //   262144 B
    float*    bet_e = (float*)(w + 95158272);         //   262144 B
    float*    cbuf  = (float*)(w + 95420416);         //   131072 B  (end 95551488)

    // weight prep (bf16 + transpose)
    transpose_cvt<<<dim3(1024 / 32, 512 / 32), 256, 0, stream>>>(ff_w1, w1t, 512, 1024);
    transpose_cvt<<<dim3(512 / 32, 1024 / 32), 256, 0, stream>>>(ff_w2, w2t, 1024, 512);
    transpose_cvt<<<dim3(256 / 32, 512 / 32), 256, 0, stream>>>(sem_w, semt, 512, 256);
    transpose_cvt<<<dim3(256 / 32, 512 / 32), 256, 0, stream>>>(epi_w, epit, 512, 256);

    // encoder, chunked over rows to bound workspace
    for (int cc = 0; cc < ML / RCH; ++cc) {
        int c0 = cc * RCH;
        gather_kernel<<<RCH, 128, 0, stream>>>(seq + c0, embed, ebc);
        mfma_gemm<1><<<dim3(1024 / 128, RCH / 128), 256, 0, stream>>>(
            ebc, w1t, ff_b1, nullptr, t1c, 1024, 512);
        mfma_gemm<3><<<dim3(512 / 128, RCH / 128), 256, 0, stream>>>(
            t1c, w2t, ff_b2, ebc, ebc, 512, 1024);     // x = ffn + e, in-place
        ln_kernel<<<RCH / 4, 256, 0, stream>>>(ebc, ln_g, ln_b);  // h, in-place
        mfma_gemm<0><<<dim3(256 / 128, RCH / 128), 256, 0, stream>>>(
            ebc, semt, sem_b, nullptr, ks_bf + (size_t)c0 * HALFD, 256, 512);
        mfma_gemm<0><<<dim3(256 / 128, RCH / 128), 256, 0, stream>>>(
            ebc, epit, epi_b, nullptr, ke_bf + (size_t)c0 * HALFD, 256, 512);
    }

    beta_kernel<<<ML / 4, 256, 0, stream>>>(ks_bf, bet_s);
    beta_kernel<<<ML / 4, 256, 0, stream>>>(ke_bf, bet_e);

    scan_kernel<<<256, 1024, 0, stream>>>(ks_bf, ke_bf, bet_s, bet_e, cbuf);

    out_gemm<<<dim3(125, 2), 256, 0, stream>>>(cbuf, out_w, out_b, outp);
}